// Round 12
// baseline (1440.715 us; speedup 1.0000x reference)
//
#include <hip/hip_runtime.h>
#include <math.h>

typedef long long ll;
typedef unsigned int u32;
typedef unsigned short u16;
typedef __attribute__((ext_vector_type(8))) short short8;
typedef __attribute__((ext_vector_type(4))) float f32x4;

#define NBLK 256          // partition blocks
#define MAXBUK 512        // supports N <= 131072
#define CHUNK_MAX 8192    // LDS edge buffer in escatter

__device__ __forceinline__ int load_idx(const void* p, int i, int is64) {
  return is64 ? (int)((const ll*)p)[i] : ((const int*)p)[i];
}

__device__ __forceinline__ u16 f2bf(float f) {
  u32 u = __float_as_uint(f);
  u += 0x7FFFu + ((u >> 16) & 1u);
  return (u16)(u >> 16);
}

// ---------- prep: W1->bf16^T + detect + zero pool + zero rec ----------
__global__ __launch_bounds__(256) void prep_kernel(
    const void* __restrict__ eidx, int ne2, const void* __restrict__ batch, int nb,
    const float* __restrict__ W1, u16* __restrict__ Wtb,
    float* __restrict__ pool, float* __restrict__ rec, int recn,
    int* __restrict__ flags) {
  int blk = blockIdx.x, t = threadIdx.x;
  if (blk < 64) {
    int g = blk * 256 + t;          // 16384 elements of W1[k][j]
    int k = g >> 7, j = g & 127;
    Wtb[j * 128 + k] = f2bf(W1[g]);
  } else if (blk == 64) {
    if (t < 192) pool[t] = 0.f;
    ll v = 0;
    if (t < 16) {
      int i = (int)((ll)(t + 1) * (ne2 / 2 - 1) / 16);
      v = ((const ll*)eidx)[i];
    } else if (t < 32) {
      int i = (int)((ll)(t - 15) * (nb / 2 - 1) / 16);
      v = ((const ll*)batch)[i];
    }
    bool bad = (v < 0 || v >= (1LL << 31));
    unsigned long long mask = __ballot(bad);
    if (t == 0) {
      flags[0] = (mask & 0xFFFFull) ? 0 : 1;          // edge_index is64
      flags[1] = (mask & 0xFFFF0000ull) ? 0 : 1;      // batch is64
    }
  } else {
    int rz = (blk - 65) * 256 + t;
    if (rz < recn) rec[rz] = 0.f;
  }
}

// ---------- K1: h = x @ W1 via MFMA bf16 (f32 acc; fused a_src1/a_dst1) ----------
__global__ __launch_bounds__(256) void gemm1_kernel(
    const float* __restrict__ x, const u16* __restrict__ Wtb,
    const float* __restrict__ att_src, const float* __restrict__ att_dst,
    u16* __restrict__ h, float* __restrict__ a_src, float* __restrict__ a_dst,
    int nn) {
  __shared__ __align__(16) char smem[64 * 136 * 2 + 128 * 136 * 2];  // 52224 B
  u16* xs = (u16*)smem;                       // [64][136]
  u16* Wt = (u16*)(smem + 64 * 136 * 2);      // [128][136]  Wt[j][k]
  float* hs = (float*)smem;                   // [64][132]   (overlay)
  int t = threadIdx.x;
  int n0 = blockIdx.x * 64;

  const uint4* W4 = (const uint4*)Wtb;        // 2048 uint4
  #pragma unroll
  for (int p = 0; p < 8; ++p) {
    int i = t + p * 256;
    int j = i >> 4, kc = (i & 15) * 8;
    *(uint4*)&Wt[j * 136 + kc] = W4[i];
  }
  #pragma unroll
  for (int p = 0; p < 4; ++p) {
    int row = p * 16 + (t >> 4);
    int c = t & 15;
    int gn = n0 + row;
    uint4 pk = make_uint4(0u, 0u, 0u, 0u);
    if (gn < nn) {
      const float4* xp = (const float4*)(x + (size_t)gn * 128 + c * 8);
      float4 f0 = xp[0], f1 = xp[1];
      pk.x = (u32)f2bf(f0.x) | ((u32)f2bf(f0.y) << 16);
      pk.y = (u32)f2bf(f0.z) | ((u32)f2bf(f0.w) << 16);
      pk.z = (u32)f2bf(f1.x) | ((u32)f2bf(f1.y) << 16);
      pk.w = (u32)f2bf(f1.z) | ((u32)f2bf(f1.w) << 16);
    }
    *(uint4*)&xs[row * 136 + c * 8] = pk;
  }
  __syncthreads();

  int lane = t & 63, wid = t >> 6;
  int lrow = lane & 15, lq = lane >> 4;
  short8 a[4];
  #pragma unroll
  for (int ks = 0; ks < 4; ++ks) {
    int row = wid * 16 + lrow;
    a[ks] = *(const short8*)&xs[row * 136 + ks * 32 + lq * 8];
  }
  f32x4 c[8];
  #pragma unroll
  for (int jt = 0; jt < 8; ++jt) c[jt] = (f32x4)(0.f);
  #pragma unroll
  for (int jt = 0; jt < 8; ++jt) {
    int j = jt * 16 + lrow;
    #pragma unroll
    for (int ks = 0; ks < 4; ++ks) {
      short8 b = *(const short8*)&Wt[j * 136 + ks * 32 + lq * 8];
      c[jt] = __builtin_amdgcn_mfma_f32_16x16x32_bf16(a[ks], b, c[jt], 0, 0, 0);
    }
  }
  __syncthreads();

  #pragma unroll
  for (int jt = 0; jt < 8; ++jt) {
    #pragma unroll
    for (int r = 0; r < 4; ++r) {
      hs[(wid * 16 + lq * 4 + r) * 132 + jt * 16 + lrow] = c[jt][r];
    }
  }
  __syncthreads();

  int q = t & 31, p = t >> 5;
  const float4 as4 = ((const float4*)att_src)[q];
  const float4 ad4 = ((const float4*)att_dst)[q];
  int head = q >> 2;
  #pragma unroll
  for (int rr = 0; rr < 8; ++rr) {
    int row = rr * 8 + p;
    int n = n0 + row;
    float4 v = *(const float4*)&hs[row * 132 + q * 4];
    float s = v.x * as4.x + v.y * as4.y + v.z * as4.z + v.w * as4.w;
    float d = v.x * ad4.x + v.y * ad4.y + v.z * ad4.z + v.w * ad4.w;
    s += __shfl_xor(s, 1); s += __shfl_xor(s, 2);
    d += __shfl_xor(d, 1); d += __shfl_xor(d, 2);
    if (n < nn) {
      uint2 pk;
      pk.x = (u32)f2bf(v.x) | ((u32)f2bf(v.y) << 16);
      pk.y = (u32)f2bf(v.z) | ((u32)f2bf(v.w) << 16);
      ((uint2*)(h + (size_t)n * 128))[q] = pk;
      if ((q & 3) == 0) { a_src[n * 8 + head] = s; a_dst[n * 8 + head] = d; }
    }
  }
}

// ---------- per-block LDS histogram of dst buckets ----------
__global__ __launch_bounds__(512) void ehist_kernel(
    const void* __restrict__ eidx, int E, int EP, int chunk,
    const int* __restrict__ flags, int* __restrict__ hist_g, int nbuk) {
  __shared__ int cnt[MAXBUK];
  int t = threadIdx.x, blk = blockIdx.x;
  if (t < MAXBUK) cnt[t] = 0;
  __syncthreads();
  int lo = blk * chunk, hi = min(lo + chunk, EP);
  int is64 = flags[0];
  for (int i = lo + t; i < hi; i += 512) {
    int d = (i < E) ? load_idx(eidx, E + i, is64) : (i - E);
    atomicAdd(&cnt[d >> 8], 1);
  }
  __syncthreads();
  if (t < nbuk) hist_g[t * NBLK + blk] = cnt[t];
}

// ---------- per-bucket scan of NBLK partial counts ----------
__global__ __launch_bounds__(256) void scan_blk(const int* __restrict__ in,
                                                int* __restrict__ out,
                                                int* __restrict__ bsums, int n) {
  int t = threadIdx.x;
  int i = blockIdx.x * 256 + t;
  int v = (i < n) ? in[i] : 0;
  int lane = t & 63, w = t >> 6;
  int s = v;
  #pragma unroll
  for (int off = 1; off < 64; off <<= 1) {
    int u = __shfl_up(s, off);
    if (lane >= off) s += u;
  }
  __shared__ int wsum[4];
  if (lane == 63) wsum[w] = s;
  __syncthreads();
  int add = 0;
  for (int k = 0; k < w; ++k) add += wsum[k];
  int incl = s + add;
  if (i < n) out[i] = incl - v;
  if (t == 255) bsums[blockIdx.x] = incl;
}

__global__ __launch_bounds__(1024) void scan_top(int* __restrict__ bsums, int nb) {
  int t = threadIdx.x;
  int v = (t < nb) ? bsums[t] : 0;
  int lane = t & 63, w = t >> 6;
  int s = v;
  #pragma unroll
  for (int off = 1; off < 64; off <<= 1) {
    int u = __shfl_up(s, off);
    if (lane >= off) s += u;
  }
  __shared__ int ws[16];
  if (lane == 63) ws[w] = s;
  __syncthreads();
  int add = 0;
  for (int k = 0; k < w; ++k) add += ws[k];
  if (t < nb) bsums[t] = s + add - v;
}

// ---------- scatter via LDS staging: dense per-run global writes ----------
__global__ __launch_bounds__(512) void escatter_kernel(
    const void* __restrict__ eidx, int E, int EP, int chunk,
    const int* __restrict__ flags, const int* __restrict__ hist_g,
    const int* __restrict__ pbase, const int* __restrict__ bsums,
    u32* __restrict__ pairs, int nbuk) {
  __shared__ int cnt[MAXBUK];
  __shared__ int lbase[MAXBUK];
  __shared__ int lcur[MAXBUK];
  __shared__ u32 buf[CHUNK_MAX];
  __shared__ int wsum[8];
  int t = threadIdx.x, blk = blockIdx.x;
  int v = 0;
  if (t < nbuk) { v = hist_g[t * NBLK + blk]; cnt[t] = v; }
  int lane = t & 63, w = t >> 6;
  int s = v;
  #pragma unroll
  for (int off = 1; off < 64; off <<= 1) {
    int u = __shfl_up(s, off);
    if (lane >= off) s += u;
  }
  if (lane == 63) wsum[w] = s;
  __syncthreads();
  int add = 0;
  for (int k = 0; k < w; ++k) add += wsum[k];
  if (t < nbuk) { lbase[t] = s + add - v; lcur[t] = s + add - v; }
  __syncthreads();
  int lo = blk * chunk, hi = min(lo + chunk, EP);
  int is64 = flags[0];
  for (int i = lo + t; i < hi; i += 512) {
    int sv, d;
    if (i < E) { sv = load_idx(eidx, i, is64); d = load_idx(eidx, E + i, is64); }
    else { sv = d = i - E; }
    int pos = atomicAdd(&lcur[d >> 8], 1);
    buf[pos] = ((u32)(d & 255) << 24) | (u32)sv;
  }
  __syncthreads();
  for (int b = w; b < nbuk; b += 8) {
    int n_b = cnt[b];
    int lb = lbase[b];
    int gb = pbase[b * NBLK + blk] + bsums[b];
    for (int k = lane; k < n_b; k += 64) {
      pairs[gb + k] = buf[lb + k];
    }
  }
}

// ---------- node1: edge-centric, LDS accumulators, dim-sliced 4-way ----------
// block = (bucket b, dim-slice q): 256 nodes x 32 dims (heads 2q, 2q+1).
// 8-lane group per edge: 64B h-slice line, 4 LDS f32 atomics, no sort needed.
__global__ __launch_bounds__(512) void node1_kernel(
    const u32* __restrict__ pairs, const int* __restrict__ bsums,
    const u16* __restrict__ h, const float* __restrict__ a_src, const float* __restrict__ a_dst,
    const float* __restrict__ b1, const float* __restrict__ W2,
    float* __restrict__ rec, int N, int EP, int nbuk) {
  __shared__ float acc[256 * 33];     // [node][32 dims + pad]
  __shared__ float dsm[256 * 2];      // [node][2 heads]
  __shared__ float adl[256 * 2];      // staged a_dst slice
  int blk = blockIdx.x;
  int b = blk >> 2, q = blk & 3;
  int t = threadIdx.x;
  for (int i = t; i < 256 * 33; i += 512) acc[i] = 0.f;
  dsm[t] = 0.f;
  {
    int nl = t >> 1, hs = t & 1;
    int gn = (b << 8) + nl;
    adl[t] = (gn < N) ? a_dst[gn * 8 + 2 * q + hs] : 0.f;
  }
  __syncthreads();
  int seg_start = bsums[b];
  int seg_end = (b + 1 < nbuk) ? bsums[b + 1] : EP;
  int g = t >> 3, l8 = t & 7;
  int hsel = l8 >> 2;                  // 0..1 within slice
  int hh = 2 * q + hsel;               // global head
  for (int i0 = seg_start; i0 < seg_end; i0 += 64) {
    int i = i0 + g;
    if (i < seg_end) {
      u32 p = pairs[i];
      int s = (int)(p & 0xFFFFFFu);
      int dl = (int)(p >> 24);
      float e = a_src[s * 8 + hh] + adl[dl * 2 + hsel];
      e = fmaxf(e, 0.2f * e);          // leaky_relu
      float ee = __expf(e);            // no max-sub: mathematically identical
      uint2 hv = *(const uint2*)(h + s * 128 + q * 32 + l8 * 4);
      float h0 = __uint_as_float(hv.x << 16);
      float h1 = __uint_as_float(hv.x & 0xFFFF0000u);
      float h2 = __uint_as_float(hv.y << 16);
      float h3 = __uint_as_float(hv.y & 0xFFFF0000u);
      float* ap = &acc[dl * 33 + l8 * 4];
      atomicAdd(ap + 0, ee * h0);
      atomicAdd(ap + 1, ee * h1);
      atomicAdd(ap + 2, ee * h2);
      atomicAdd(ap + 3, ee * h3);
      if ((l8 & 3) == 0) atomicAdd(&dsm[dl * 2 + hsel], ee);
    }
  }
  __syncthreads();
  // finalize slice: ELU + partial W2 projection -> atomic into rec
  for (int rep = 0; rep < 4; ++rep) {
    int nl = rep * 64 + g;
    int n = (b << 8) + nl;
    if (n < N) {
      float denom = dsm[nl * 2 + hsel];
      float p0 = 0.f, p1 = 0.f;
      if (denom > 0.f) {
        float inv = 1.f / denom;
        #pragma unroll
        for (int k = 0; k < 4; ++k) {
          int dim = l8 * 4 + k;
          int j = q * 32 + dim;
          float o = acc[nl * 33 + dim] * inv + b1[j];
          o = (o > 0.f) ? o : expm1f(o);   // ELU (per-dim, slice-local)
          p0 = fmaf(o, W2[j * 2],     p0);
          p1 = fmaf(o, W2[j * 2 + 1], p1);
        }
      }
      p0 += __shfl_xor(p0, 1); p0 += __shfl_xor(p0, 2); p0 += __shfl_xor(p0, 4);
      p1 += __shfl_xor(p1, 1); p1 += __shfl_xor(p1, 2); p1 += __shfl_xor(p1, 4);
      if (l8 == 0) {
        atomicAdd(&rec[n * 2],     p0);
        atomicAdd(&rec[n * 2 + 1], p1);
      }
    }
  }
}

// ---------- node2: edge-centric, LDS accumulators + graph mean-pool ----------
__global__ __launch_bounds__(512) void node2_kernel(
    const u32* __restrict__ pairs, const int* __restrict__ bsums,
    const float* __restrict__ rec, const float* __restrict__ b2,
    const float* __restrict__ att_s2, const float* __restrict__ att_d2,
    const void* __restrict__ batch, const int* __restrict__ flags,
    float* __restrict__ pool, int N, int EP, int nbuk) {
  __shared__ float acc0[256], acc1[256], dsl[256], ad2l[256];
  __shared__ float psum[128];
  __shared__ float pcnt[64];
  int b = blockIdx.x, t = threadIdx.x;
  float s0 = att_s2[0], s1 = att_s2[1];
  if (t < 256) {
    acc0[t] = 0.f; acc1[t] = 0.f; dsl[t] = 0.f;
    int gn = (b << 8) + t;
    float d0 = att_d2[0], d1 = att_d2[1];
    if (gn < N) {
      float2 r = *(const float2*)(rec + gn * 2);
      ad2l[t] = r.x * d0 + r.y * d1;
    } else ad2l[t] = 0.f;
  }
  if (t < 128) psum[t] = 0.f;
  if (t < 64) pcnt[t] = 0.f;
  __syncthreads();
  int seg_start = bsums[b];
  int seg_end = (b + 1 < nbuk) ? bsums[b + 1] : EP;
  for (int i = seg_start + t; i < seg_end; i += 512) {
    u32 p = pairs[i];
    int s = (int)(p & 0xFFFFFFu);
    int dl = (int)(p >> 24);
    float2 r = *(const float2*)(rec + s * 2);
    float e = r.x * s0 + r.y * s1 + ad2l[dl];
    e = fmaxf(e, 0.2f * e);
    float ee = __expf(e);
    atomicAdd(&acc0[dl], ee * r.x);
    atomicAdd(&acc1[dl], ee * r.y);
    atomicAdd(&dsl[dl], ee);
  }
  __syncthreads();
  int b64 = flags[1];
  if (t < 256) {
    int n = (b << 8) + t;
    if (n < N && dsl[t] > 0.f) {
      float o0 = acc0[t] / dsl[t] + b2[0];
      float o1 = acc1[t] / dsl[t] + b2[1];
      int gg = load_idx(batch, n, b64);
      atomicAdd(&psum[gg * 2], o0);
      atomicAdd(&psum[gg * 2 + 1], o1);
      atomicAdd(&pcnt[gg], 1.f);
    }
  }
  __syncthreads();
  if (t < 64 && pcnt[t] > 0.f) {
    atomicAdd(&pool[t * 2], psum[t * 2]);
    atomicAdd(&pool[t * 2 + 1], psum[t * 2 + 1]);
    atomicAdd(&pool[128 + t], pcnt[t]);
  }
}

// ---------- mean + log_softmax ----------
__global__ void finalize_kernel(const float* __restrict__ pool, float* __restrict__ out) {
  int g = threadIdx.x;
  if (g < 64) {
    float c = fmaxf(pool[128 + g], 1.f);
    float p0 = pool[g * 2] / c, p1 = pool[g * 2 + 1] / c;
    float m = fmaxf(p0, p1);
    float lse = m + logf(expf(p0 - m) + expf(p1 - m));
    out[g * 2] = p0 - lse;
    out[g * 2 + 1] = p1 - lse;
  }
}

extern "C" void kernel_launch(void* const* d_in, const int* in_sizes, int n_in,
                              void* d_out, int out_size, void* d_ws, size_t ws_size,
                              hipStream_t stream) {
  const float* x        = (const float*)d_in[0];
  const void* eidx      = d_in[1];
  const void* batch     = d_in[2];
  const float* W1       = (const float*)d_in[3];
  const float* att_src1 = (const float*)d_in[4];
  const float* att_dst1 = (const float*)d_in[5];
  const float* b1       = (const float*)d_in[6];
  const float* W2       = (const float*)d_in[7];
  const float* att_src2 = (const float*)d_in[8];
  const float* att_dst2 = (const float*)d_in[9];
  const float* b2       = (const float*)d_in[10];
  float* out = (float*)d_out;

  int N = in_sizes[0] / 128;
  int E = in_sizes[1] / 2;
  int EP = E + N;
  int NBUK = (N + 255) >> 8;         // <= MAXBUK for N <= 131072
  int NC = NBUK * NBLK;
  int chunk = (((EP + NBLK - 1) / NBLK) + 1) & ~1;   // <= CHUNK_MAX
  int recn = 2 * N;

  char* ws = (char*)d_ws;
  size_t o = 0;
  auto alloc = [&](size_t bytes) -> void* {
    void* p = ws + o;
    o += (bytes + 255) & ~(size_t)255;
    return p;
  };
  u16*   h      = (u16*)alloc((size_t)N * 128 * 2);    // 25.6 MB bf16
  u16*   Wtb    = (u16*)alloc(128 * 128 * 2);          // bf16 W1^T
  float* a_src1 = (float*)alloc((size_t)N * 8 * 4);
  float* a_dst1 = (float*)alloc((size_t)N * 8 * 4);
  int*   hist_g = (int*)alloc((size_t)NC * 4);         // 400 KB
  int*   pbase  = (int*)alloc((size_t)NC * 4);
  int*   bsums  = (int*)alloc((size_t)(NBUK + 1) * 4);
  u32*   pairs  = (u32*)alloc((size_t)EP * 4);         // 6.8 MB packed
  float* rec    = (float*)alloc((size_t)recn * 4);     // {p0,p1} per node
  float* pool   = (float*)alloc(192 * 4);
  int*   flags  = (int*)alloc(2 * 4);

  int prep_grid = 65 + (recn + 255) / 256;
  prep_kernel<<<prep_grid, 256, 0, stream>>>(eidx, 2 * E, batch, N, W1, Wtb,
                                             pool, rec, recn, flags);
  gemm1_kernel<<<(N + 63) / 64, 256, 0, stream>>>(x, Wtb, att_src1, att_dst1,
                                                  h, a_src1, a_dst1, N);
  ehist_kernel<<<NBLK, 512, 0, stream>>>(eidx, E, EP, chunk, flags, hist_g, NBUK);
  scan_blk<<<NBUK, 256, 0, stream>>>(hist_g, pbase, bsums, NC);
  scan_top<<<1, 1024, 0, stream>>>(bsums, NBUK);
  escatter_kernel<<<NBLK, 512, 0, stream>>>(eidx, E, EP, chunk, flags, hist_g,
                                            pbase, bsums, pairs, NBUK);
  node1_kernel<<<NBUK * 4, 512, 0, stream>>>(pairs, bsums, h, a_src1, a_dst1,
                                             b1, W2, rec, N, EP, NBUK);
  node2_kernel<<<NBUK, 512, 0, stream>>>(pairs, bsums, rec, b2,
                                         att_src2, att_dst2, batch, flags,
                                         pool, N, EP, NBUK);
  finalize_kernel<<<1, 64, 0, stream>>>(pool, out);
}

// Round 13
// 222.746 us; speedup vs baseline: 6.4680x; 6.4680x over previous
//
#include <hip/hip_runtime.h>
#include <math.h>

typedef long long ll;
typedef unsigned int u32;
typedef unsigned short u16;
typedef __attribute__((ext_vector_type(8))) short short8;
typedef __attribute__((ext_vector_type(4))) float f32x4;

#define NBLK 256          // partition blocks
#define MAXBUK 512        // supports N <= 131072
#define CHUNK_MAX 8192    // LDS edge buffer in escatter
#define SBUF 8192         // bfinal LDS pairs buffer (bucket seg ~4.4K)

__device__ __forceinline__ int load_idx(const void* p, int i, int is64) {
  return is64 ? (int)((const ll*)p)[i] : ((const int*)p)[i];
}

__device__ __forceinline__ u16 f2bf(float f) {
  u32 u = __float_as_uint(f);
  u += 0x7FFFu + ((u >> 16) & 1u);
  return (u16)(u >> 16);
}

// ---------- prep: W1->bf16^T + detect(parallel) + zero pool + ssrc pad ----------
__global__ __launch_bounds__(256) void prep_kernel(
    const void* __restrict__ eidx, int ne2, const void* __restrict__ batch, int nb,
    const float* __restrict__ W1, u16* __restrict__ Wtb,
    float* __restrict__ pool, int* __restrict__ ssrc, int EP,
    int* __restrict__ flags) {
  int blk = blockIdx.x, t = threadIdx.x;
  if (blk < 64) {
    int g = blk * 256 + t;          // 16384 elements of W1[k][j]
    int k = g >> 7, j = g & 127;
    Wtb[j * 128 + k] = f2bf(W1[g]);
  } else {
    if (t < 192) pool[t] = 0.f;
    ssrc[EP + t] = 0;               // 256-int zero pad (clamp-free node1 reads)
    ll v = 0;
    if (t < 16) {
      int i = (int)((ll)(t + 1) * (ne2 / 2 - 1) / 16);
      v = ((const ll*)eidx)[i];
    } else if (t < 32) {
      int i = (int)((ll)(t - 15) * (nb / 2 - 1) / 16);
      v = ((const ll*)batch)[i];
    }
    bool bad = (v < 0 || v >= (1LL << 31));
    unsigned long long mask = __ballot(bad);
    if (t == 0) {
      flags[0] = (mask & 0xFFFFull) ? 0 : 1;          // edge_index is64
      flags[1] = (mask & 0xFFFF0000ull) ? 0 : 1;      // batch is64
    }
  }
}

// ---------- K1: h = x @ W1 via MFMA bf16 (f32 acc; fused a_src1/a_dst1) ----------
__global__ __launch_bounds__(256) void gemm1_kernel(
    const float* __restrict__ x, const u16* __restrict__ Wtb,
    const float* __restrict__ att_src, const float* __restrict__ att_dst,
    u16* __restrict__ h, float* __restrict__ a_src, float* __restrict__ a_dst,
    int nn) {
  __shared__ __align__(16) char smem[64 * 136 * 2 + 128 * 136 * 2];  // 52224 B
  u16* xs = (u16*)smem;                       // [64][136]
  u16* Wt = (u16*)(smem + 64 * 136 * 2);      // [128][136]  Wt[j][k]
  float* hs = (float*)smem;                   // [64][132]   (overlay)
  int t = threadIdx.x;
  int n0 = blockIdx.x * 64;

  const uint4* W4 = (const uint4*)Wtb;        // 2048 uint4
  #pragma unroll
  for (int p = 0; p < 8; ++p) {
    int i = t + p * 256;
    int j = i >> 4, kc = (i & 15) * 8;
    *(uint4*)&Wt[j * 136 + kc] = W4[i];
  }
  #pragma unroll
  for (int p = 0; p < 4; ++p) {
    int row = p * 16 + (t >> 4);
    int c = t & 15;
    int gn = n0 + row;
    uint4 pk = make_uint4(0u, 0u, 0u, 0u);
    if (gn < nn) {
      const float4* xp = (const float4*)(x + (size_t)gn * 128 + c * 8);
      float4 f0 = xp[0], f1 = xp[1];
      pk.x = (u32)f2bf(f0.x) | ((u32)f2bf(f0.y) << 16);
      pk.y = (u32)f2bf(f0.z) | ((u32)f2bf(f0.w) << 16);
      pk.z = (u32)f2bf(f1.x) | ((u32)f2bf(f1.y) << 16);
      pk.w = (u32)f2bf(f1.z) | ((u32)f2bf(f1.w) << 16);
    }
    *(uint4*)&xs[row * 136 + c * 8] = pk;
  }
  __syncthreads();

  int lane = t & 63, wid = t >> 6;
  int lrow = lane & 15, lq = lane >> 4;
  short8 a[4];
  #pragma unroll
  for (int ks = 0; ks < 4; ++ks) {
    int row = wid * 16 + lrow;
    a[ks] = *(const short8*)&xs[row * 136 + ks * 32 + lq * 8];
  }
  f32x4 c[8];
  #pragma unroll
  for (int jt = 0; jt < 8; ++jt) c[jt] = (f32x4)(0.f);
  #pragma unroll
  for (int jt = 0; jt < 8; ++jt) {
    int j = jt * 16 + lrow;
    #pragma unroll
    for (int ks = 0; ks < 4; ++ks) {
      short8 b = *(const short8*)&Wt[j * 136 + ks * 32 + lq * 8];
      c[jt] = __builtin_amdgcn_mfma_f32_16x16x32_bf16(a[ks], b, c[jt], 0, 0, 0);
    }
  }
  __syncthreads();

  #pragma unroll
  for (int jt = 0; jt < 8; ++jt) {
    #pragma unroll
    for (int r = 0; r < 4; ++r) {
      hs[(wid * 16 + lq * 4 + r) * 132 + jt * 16 + lrow] = c[jt][r];
    }
  }
  __syncthreads();

  int q = t & 31, p = t >> 5;
  const float4 as4 = ((const float4*)att_src)[q];
  const float4 ad4 = ((const float4*)att_dst)[q];
  int head = q >> 2;
  #pragma unroll
  for (int rr = 0; rr < 8; ++rr) {
    int row = rr * 8 + p;
    int n = n0 + row;
    float4 v = *(const float4*)&hs[row * 132 + q * 4];
    float s = v.x * as4.x + v.y * as4.y + v.z * as4.z + v.w * as4.w;
    float d = v.x * ad4.x + v.y * ad4.y + v.z * ad4.z + v.w * ad4.w;
    s += __shfl_xor(s, 1); s += __shfl_xor(s, 2);
    d += __shfl_xor(d, 1); d += __shfl_xor(d, 2);
    if (n < nn) {
      uint2 pk;
      pk.x = (u32)f2bf(v.x) | ((u32)f2bf(v.y) << 16);
      pk.y = (u32)f2bf(v.z) | ((u32)f2bf(v.w) << 16);
      ((uint2*)(h + (size_t)n * 128))[q] = pk;
      if ((q & 3) == 0) { a_src[n * 8 + head] = s; a_dst[n * 8 + head] = d; }
    }
  }
}

// ---------- per-block LDS histogram of dst buckets ----------
__global__ __launch_bounds__(512) void ehist_kernel(
    const void* __restrict__ eidx, int E, int EP, int chunk,
    const int* __restrict__ flags, int* __restrict__ hist_g, int nbuk) {
  __shared__ int cnt[MAXBUK];
  int t = threadIdx.x, blk = blockIdx.x;
  if (t < MAXBUK) cnt[t] = 0;
  __syncthreads();
  int lo = blk * chunk, hi = min(lo + chunk, EP);
  int is64 = flags[0];
  for (int i = lo + t; i < hi; i += 512) {
    int d = (i < E) ? load_idx(eidx, E + i, is64) : (i - E);
    atomicAdd(&cnt[d >> 8], 1);
  }
  __syncthreads();
  if (t < nbuk) hist_g[t * NBLK + blk] = cnt[t];
}

// ---------- per-bucket scan of NBLK partial counts ----------
__global__ __launch_bounds__(256) void scan_blk(const int* __restrict__ in,
                                                int* __restrict__ out,
                                                int* __restrict__ bsums, int n) {
  int t = threadIdx.x;
  int i = blockIdx.x * 256 + t;
  int v = (i < n) ? in[i] : 0;
  int lane = t & 63, w = t >> 6;
  int s = v;
  #pragma unroll
  for (int off = 1; off < 64; off <<= 1) {
    int u = __shfl_up(s, off);
    if (lane >= off) s += u;
  }
  __shared__ int wsum[4];
  if (lane == 63) wsum[w] = s;
  __syncthreads();
  int add = 0;
  for (int k = 0; k < w; ++k) add += wsum[k];
  int incl = s + add;
  if (i < n) out[i] = incl - v;
  if (t == 255) bsums[blockIdx.x] = incl;
}

__global__ __launch_bounds__(1024) void scan_top(int* __restrict__ bsums, int nb) {
  int t = threadIdx.x;
  int v = (t < nb) ? bsums[t] : 0;
  int lane = t & 63, w = t >> 6;
  int s = v;
  #pragma unroll
  for (int off = 1; off < 64; off <<= 1) {
    int u = __shfl_up(s, off);
    if (lane >= off) s += u;
  }
  __shared__ int ws[16];
  if (lane == 63) ws[w] = s;
  __syncthreads();
  int add = 0;
  for (int k = 0; k < w; ++k) add += ws[k];
  if (t < nb) bsums[t] = s + add - v;
}

// ---------- scatter via LDS staging: dense per-run global writes ----------
__global__ __launch_bounds__(512) void escatter_kernel(
    const void* __restrict__ eidx, int E, int EP, int chunk,
    const int* __restrict__ flags, const int* __restrict__ hist_g,
    const int* __restrict__ pbase, const int* __restrict__ bsums,
    u32* __restrict__ pairs, int nbuk) {
  __shared__ int cnt[MAXBUK];
  __shared__ int lbase[MAXBUK];
  __shared__ int lcur[MAXBUK];
  __shared__ u32 buf[CHUNK_MAX];
  __shared__ int wsum[8];
  int t = threadIdx.x, blk = blockIdx.x;
  int v = 0;
  if (t < nbuk) { v = hist_g[t * NBLK + blk]; cnt[t] = v; }
  int lane = t & 63, w = t >> 6;
  int s = v;
  #pragma unroll
  for (int off = 1; off < 64; off <<= 1) {
    int u = __shfl_up(s, off);
    if (lane >= off) s += u;
  }
  if (lane == 63) wsum[w] = s;
  __syncthreads();
  int add = 0;
  for (int k = 0; k < w; ++k) add += wsum[k];
  if (t < nbuk) { lbase[t] = s + add - v; lcur[t] = s + add - v; }
  __syncthreads();
  int lo = blk * chunk, hi = min(lo + chunk, EP);
  int is64 = flags[0];
  for (int i = lo + t; i < hi; i += 512) {
    int sv, d;
    if (i < E) { sv = load_idx(eidx, i, is64); d = load_idx(eidx, E + i, is64); }
    else { sv = d = i - E; }
    int pos = atomicAdd(&lcur[d >> 8], 1);
    buf[pos] = ((u32)(d & 255) << 24) | (u32)sv;
  }
  __syncthreads();
  for (int b = w; b < nbuk; b += 8) {
    int n_b = cnt[b];
    int lb = lbase[b];
    int gb = pbase[b * NBLK + blk] + bsums[b];
    for (int k = lane; k < n_b; k += 64) {
      pairs[gb + k] = buf[lb + k];
    }
  }
}

// ---------- per-bucket local sort: single global read, LDS-buffered ----------
__global__ __launch_bounds__(256) void bfinal_kernel(
    const u32* __restrict__ pairs, const int* __restrict__ pbase,
    const int* __restrict__ bsums,
    int* __restrict__ offs, int* __restrict__ ends, int* __restrict__ ssrc,
    int N, int EP, int nbuk) {
  int b = blockIdx.x, t = threadIdx.x;
  int nb0 = b << 8;
  __shared__ u32 sbuf[SBUF];
  __shared__ int cnt[256];
  __shared__ int cur[256];
  __shared__ int wsum[4];
  cnt[t] = 0;
  __syncthreads();
  int seg_start = pbase[b * NBLK] + bsums[b];
  int seg_end = (b + 1 < nbuk) ? (pbase[(b + 1) * NBLK] + bsums[b + 1]) : EP;
  int len = seg_end - seg_start;
  for (int i = t; i < len; i += 256) {
    u32 p = pairs[seg_start + i];
    if (i < SBUF) sbuf[i] = p;
    atomicAdd(&cnt[p >> 24], 1);
  }
  __syncthreads();
  int v = cnt[t];
  int lane = t & 63, w = t >> 6;
  int s = v;
  #pragma unroll
  for (int off = 1; off < 64; off <<= 1) {
    int u = __shfl_up(s, off);
    if (lane >= off) s += u;
  }
  if (lane == 63) wsum[w] = s;
  __syncthreads();
  int add = 0;
  for (int k = 0; k < w; ++k) add += wsum[k];
  int excl = s + add - v;
  cur[t] = excl;
  int node = nb0 + t;
  if (node < N) { offs[node] = seg_start + excl; ends[node] = seg_start + excl + v; }
  __syncthreads();
  for (int i = t; i < len; i += 256) {
    u32 p = (i < SBUF) ? sbuf[i] : pairs[seg_start + i];
    int pos = atomicAdd(&cur[p >> 24], 1);
    ssrc[seg_start + pos] = (int)(p & 0xFFFFFFu);
  }
}

// ---------- layer-1 aggregation + ELU + layer-2 projection ----------
// 16 lanes/node, 4 nodes/wave; clamp-free ssrc reads (256-int zero pad).
__global__ __launch_bounds__(256) void node1_kernel(
    const int* __restrict__ ssrc, const int* __restrict__ offs, const int* __restrict__ ends,
    const u16* __restrict__ h, const float* __restrict__ a_src, const float* __restrict__ a_dst,
    const float* __restrict__ b1, const float* __restrict__ W2,
    const float* __restrict__ att_s2, const float* __restrict__ att_d2,
    float4* __restrict__ rec, int nn) {
  int t = threadIdx.x;
  int wid = t >> 6, lane = t & 63;
  int grp = lane >> 4, lg = lane & 15;      // 4 node-groups of 16 lanes
  int n = blockIdx.x * 16 + wid * 4 + grp;
  bool nvalid = (n < nn);
  int nc = nvalid ? n : (nn - 1);
  int hh = lg >> 1;                          // head for this lane's 8 dims
  float adst = a_dst[nc * 8 + hh];
  int beg = offs[nc], end = ends[nc];
  int deg = nvalid ? (end - beg) : 0;
  int maxd = deg;
  maxd = max(maxd, __shfl_xor(maxd, 16));
  maxd = max(maxd, __shfl_xor(maxd, 32));    // wave-wide max degree
  float acc[8];
  #pragma unroll
  for (int k = 0; k < 8; ++k) acc[k] = 0.f;
  float dsum = 0.f;
  const u32* h32 = (const u32*)h;
  for (int it = 0; it < maxd; it += 4) {
    int s4[4]; float ea4[4]; uint4 v4[4];
    #pragma unroll
    for (int u = 0; u < 4; ++u) {
      s4[u] = ssrc[beg + it + u];            // pad-safe: ee=0 masks overreads
    }
    #pragma unroll
    for (int u = 0; u < 4; ++u) {
      v4[u]  = *(const uint4*)(h32 + s4[u] * 64 + lg * 4);
      ea4[u] = a_src[s4[u] * 8 + hh];
    }
    #pragma unroll
    for (int u = 0; u < 4; ++u) {
      float e = ea4[u] + adst;
      e = fmaxf(e, 0.2f * e);                 // leaky_relu
      float ee = (it + u < deg) ? __expf(e) : 0.f;
      dsum += ee;
      acc[0] = fmaf(ee, __uint_as_float(v4[u].x << 16),          acc[0]);
      acc[1] = fmaf(ee, __uint_as_float(v4[u].x & 0xFFFF0000u),  acc[1]);
      acc[2] = fmaf(ee, __uint_as_float(v4[u].y << 16),          acc[2]);
      acc[3] = fmaf(ee, __uint_as_float(v4[u].y & 0xFFFF0000u),  acc[3]);
      acc[4] = fmaf(ee, __uint_as_float(v4[u].z << 16),          acc[4]);
      acc[5] = fmaf(ee, __uint_as_float(v4[u].z & 0xFFFF0000u),  acc[5]);
      acc[6] = fmaf(ee, __uint_as_float(v4[u].w << 16),          acc[6]);
      acc[7] = fmaf(ee, __uint_as_float(v4[u].w & 0xFFFF0000u),  acc[7]);
    }
  }
  float inv = 1.f / dsum;                     // lane-local denominator
  float p0 = 0.f, p1 = 0.f;
  #pragma unroll
  for (int k = 0; k < 8; ++k) {
    int j = lg * 8 + k;
    float o = acc[k] * inv + b1[j];
    o = (o > 0.f) ? o : expm1f(o);            // ELU
    p0 = fmaf(o, W2[j * 2],     p0);
    p1 = fmaf(o, W2[j * 2 + 1], p1);
  }
  #pragma unroll
  for (int m = 1; m < 16; m <<= 1) { p0 += __shfl_xor(p0, m); p1 += __shfl_xor(p1, m); }
  if (nvalid && lg == 0) {
    rec[n] = make_float4(p0, p1,
                         p0 * att_s2[0] + p1 * att_s2[1],
                         p0 * att_d2[0] + p1 * att_d2[1]);
  }
}

// ---------- layer-2 aggregation + graph mean-pool (8-lane group per node) ----------
__global__ __launch_bounds__(256) void node2_kernel(
    const int* __restrict__ ssrc, const int* __restrict__ offs, const int* __restrict__ ends,
    const float4* __restrict__ rec, const float* __restrict__ b2,
    const void* __restrict__ batch, const int* __restrict__ flags,
    float* __restrict__ pool, int nn) {
  __shared__ float psum[128];
  __shared__ float pcnt[64];
  int t = threadIdx.x;
  if (t < 128) psum[t] = 0.f;
  if (t < 64) pcnt[t] = 0.f;
  __syncthreads();
  int grp = t >> 3, lane8 = t & 7;    // 32 groups of 8 lanes
  int b64 = flags[1];
  int n = blockIdx.x * 32 + grp;
  if (n < nn) {
    float adst = rec[n].w;
    int beg = offs[n], end = ends[n];
    float acc0 = 0.f, acc1 = 0.f, dsum = 0.f;
    for (int idx = beg + lane8; idx < end; idx += 8) {
      int s = ssrc[idx];
      float4 r = rec[s];                // one 16B gather: {p0,p1,as2,ad2}
      float e = r.z + adst;
      e = (e < 0.f) ? 0.2f * e : e;
      float ee = __expf(e);
      acc0 = fmaf(ee, r.x, acc0);
      acc1 = fmaf(ee, r.y, acc1);
      dsum += ee;
    }
    #pragma unroll
    for (int m = 1; m < 8; m <<= 1) {
      acc0 += __shfl_xor(acc0, m);
      acc1 += __shfl_xor(acc1, m);
      dsum += __shfl_xor(dsum, m);
    }
    if (lane8 == 0) {
      float o0 = acc0 / dsum + b2[0];
      float o1 = acc1 / dsum + b2[1];
      int g = load_idx(batch, n, b64);
      atomicAdd(&psum[g * 2], o0);
      atomicAdd(&psum[g * 2 + 1], o1);
      atomicAdd(&pcnt[g], 1.f);
    }
  }
  __syncthreads();
  if (t < 64 && pcnt[t] > 0.f) {
    atomicAdd(&pool[t * 2], psum[t * 2]);
    atomicAdd(&pool[t * 2 + 1], psum[t * 2 + 1]);
    atomicAdd(&pool[128 + t], pcnt[t]);
  }
}

// ---------- mean + log_softmax ----------
__global__ void finalize_kernel(const float* __restrict__ pool, float* __restrict__ out) {
  int g = threadIdx.x;
  if (g < 64) {
    float c = fmaxf(pool[128 + g], 1.f);
    float p0 = pool[g * 2] / c, p1 = pool[g * 2 + 1] / c;
    float m = fmaxf(p0, p1);
    float lse = m + logf(expf(p0 - m) + expf(p1 - m));
    out[g * 2] = p0 - lse;
    out[g * 2 + 1] = p1 - lse;
  }
}

extern "C" void kernel_launch(void* const* d_in, const int* in_sizes, int n_in,
                              void* d_out, int out_size, void* d_ws, size_t ws_size,
                              hipStream_t stream) {
  const float* x        = (const float*)d_in[0];
  const void* eidx      = d_in[1];
  const void* batch     = d_in[2];
  const float* W1       = (const float*)d_in[3];
  const float* att_src1 = (const float*)d_in[4];
  const float* att_dst1 = (const float*)d_in[5];
  const float* b1       = (const float*)d_in[6];
  const float* W2       = (const float*)d_in[7];
  const float* att_src2 = (const float*)d_in[8];
  const float* att_dst2 = (const float*)d_in[9];
  const float* b2       = (const float*)d_in[10];
  float* out = (float*)d_out;

  int N = in_sizes[0] / 128;
  int E = in_sizes[1] / 2;
  int EP = E + N;
  int NBUK = (N + 255) >> 8;         // <= MAXBUK for N <= 131072
  int NC = NBUK * NBLK;
  int chunk = (((EP + NBLK - 1) / NBLK) + 1) & ~1;   // <= CHUNK_MAX

  char* ws = (char*)d_ws;
  size_t o = 0;
  auto alloc = [&](size_t bytes) -> void* {
    void* p = ws + o;
    o += (bytes + 255) & ~(size_t)255;
    return p;
  };
  u16*   h      = (u16*)alloc((size_t)N * 128 * 2);    // 25.6 MB bf16
  u16*   Wtb    = (u16*)alloc(128 * 128 * 2);          // bf16 W1^T
  float* a_src1 = (float*)alloc((size_t)N * 8 * 4);
  float* a_dst1 = (float*)alloc((size_t)N * 8 * 4);
  int*   offs   = (int*)alloc((size_t)N * 4);
  int*   ends   = (int*)alloc((size_t)N * 4);
  int*   hist_g = (int*)alloc((size_t)NC * 4);         // 400 KB
  int*   pbase  = (int*)alloc((size_t)NC * 4);
  int*   bsums  = (int*)alloc((size_t)(NBUK + 1) * 4);
  u32*   pairs  = (u32*)alloc((size_t)EP * 4);         // 6.8 MB packed
  int*   ssrc   = (int*)alloc(((size_t)EP + 256) * 4); // +256 zero pad
  float4* rec   = (float4*)alloc((size_t)N * 16);      // {p0,p1,as2,ad2}
  float* pool   = (float*)alloc(192 * 4);
  int*   flags  = (int*)alloc(2 * 4);

  prep_kernel<<<65, 256, 0, stream>>>(eidx, 2 * E, batch, N, W1, Wtb, pool,
                                      ssrc, EP, flags);
  gemm1_kernel<<<(N + 63) / 64, 256, 0, stream>>>(x, Wtb, att_src1, att_dst1,
                                                  h, a_src1, a_dst1, N);
  ehist_kernel<<<NBLK, 512, 0, stream>>>(eidx, E, EP, chunk, flags, hist_g, NBUK);
  scan_blk<<<NBUK, 256, 0, stream>>>(hist_g, pbase, bsums, NC);
  scan_top<<<1, 1024, 0, stream>>>(bsums, NBUK);
  escatter_kernel<<<NBLK, 512, 0, stream>>>(eidx, E, EP, chunk, flags, hist_g,
                                            pbase, bsums, pairs, NBUK);
  bfinal_kernel<<<NBUK, 256, 0, stream>>>(pairs, pbase, bsums, offs, ends, ssrc,
                                          N, EP, NBUK);
  node1_kernel<<<(N + 15) / 16, 256, 0, stream>>>(ssrc, offs, ends, h, a_src1, a_dst1,
                                                  b1, W2, att_src2, att_dst2,
                                                  rec, N);
  node2_kernel<<<(N + 31) / 32, 256, 0, stream>>>(ssrc, offs, ends, rec,
                                                  b2, batch, flags, pool, N);
  finalize_kernel<<<1, 64, 0, stream>>>(pool, out);
}

// Round 14
// 205.101 us; speedup vs baseline: 7.0244x; 1.0860x over previous
//
#include <hip/hip_runtime.h>
#include <math.h>

typedef long long ll;
typedef unsigned int u32;
typedef unsigned short u16;
typedef __attribute__((ext_vector_type(8))) short short8;
typedef __attribute__((ext_vector_type(4))) float f32x4;

#define NBLK 256          // partition blocks
#define MAXBUK 512        // supports N <= 131072
#define CHUNK_MAX 8192    // LDS edge buffer in escatter

__device__ __forceinline__ int load_idx(const void* p, int i, int is64) {
  return is64 ? (int)((const ll*)p)[i] : ((const int*)p)[i];
}

__device__ __forceinline__ u16 f2bf(float f) {
  u32 u = __float_as_uint(f);
  u += 0x7FFFu + ((u >> 16) & 1u);
  return (u16)(u >> 16);
}

// ---------- prep: W1->bf16^T + detect(parallel) + zero pool ----------
__global__ __launch_bounds__(256) void prep_kernel(
    const void* __restrict__ eidx, int ne2, const void* __restrict__ batch, int nb,
    const float* __restrict__ W1, u16* __restrict__ Wtb,
    float* __restrict__ pool, int* __restrict__ flags) {
  int blk = blockIdx.x, t = threadIdx.x;
  if (blk < 64) {
    int g = blk * 256 + t;          // 16384 elements of W1[k][j]
    int k = g >> 7, j = g & 127;
    Wtb[j * 128 + k] = f2bf(W1[g]);
  } else {
    if (t < 192) pool[t] = 0.f;
    ll v = 0;
    if (t < 16) {
      int i = (int)((ll)(t + 1) * (ne2 / 2 - 1) / 16);
      v = ((const ll*)eidx)[i];
    } else if (t < 32) {
      int i = (int)((ll)(t - 15) * (nb / 2 - 1) / 16);
      v = ((const ll*)batch)[i];
    }
    bool bad = (v < 0 || v >= (1LL << 31));
    unsigned long long mask = __ballot(bad);
    if (t == 0) {
      flags[0] = (mask & 0xFFFFull) ? 0 : 1;          // edge_index is64
      flags[1] = (mask & 0xFFFF0000ull) ? 0 : 1;      // batch is64
    }
  }
}

// ---------- K1: h = x @ W1 via MFMA bf16 (f32 acc; fused a_src1/a_dst1) ----------
__global__ __launch_bounds__(256) void gemm1_kernel(
    const float* __restrict__ x, const u16* __restrict__ Wtb,
    const float* __restrict__ att_src, const float* __restrict__ att_dst,
    u16* __restrict__ h, float* __restrict__ a_src, float* __restrict__ a_dst,
    int nn) {
  __shared__ __align__(16) char smem[64 * 136 * 2 + 128 * 136 * 2];  // 52224 B
  u16* xs = (u16*)smem;                       // [64][136]
  u16* Wt = (u16*)(smem + 64 * 136 * 2);      // [128][136]  Wt[j][k]
  float* hs = (float*)smem;                   // [64][132]   (overlay)
  int t = threadIdx.x;
  int n0 = blockIdx.x * 64;

  const uint4* W4 = (const uint4*)Wtb;        // 2048 uint4
  #pragma unroll
  for (int p = 0; p < 8; ++p) {
    int i = t + p * 256;
    int j = i >> 4, kc = (i & 15) * 8;
    *(uint4*)&Wt[j * 136 + kc] = W4[i];
  }
  #pragma unroll
  for (int p = 0; p < 4; ++p) {
    int row = p * 16 + (t >> 4);
    int c = t & 15;
    int gn = n0 + row;
    uint4 pk = make_uint4(0u, 0u, 0u, 0u);
    if (gn < nn) {
      const float4* xp = (const float4*)(x + (size_t)gn * 128 + c * 8);
      float4 f0 = xp[0], f1 = xp[1];
      pk.x = (u32)f2bf(f0.x) | ((u32)f2bf(f0.y) << 16);
      pk.y = (u32)f2bf(f0.z) | ((u32)f2bf(f0.w) << 16);
      pk.z = (u32)f2bf(f1.x) | ((u32)f2bf(f1.y) << 16);
      pk.w = (u32)f2bf(f1.z) | ((u32)f2bf(f1.w) << 16);
    }
    *(uint4*)&xs[row * 136 + c * 8] = pk;
  }
  __syncthreads();

  int lane = t & 63, wid = t >> 6;
  int lrow = lane & 15, lq = lane >> 4;
  short8 a[4];
  #pragma unroll
  for (int ks = 0; ks < 4; ++ks) {
    int row = wid * 16 + lrow;
    a[ks] = *(const short8*)&xs[row * 136 + ks * 32 + lq * 8];
  }
  f32x4 c[8];
  #pragma unroll
  for (int jt = 0; jt < 8; ++jt) c[jt] = (f32x4)(0.f);
  #pragma unroll
  for (int jt = 0; jt < 8; ++jt) {
    int j = jt * 16 + lrow;
    #pragma unroll
    for (int ks = 0; ks < 4; ++ks) {
      short8 b = *(const short8*)&Wt[j * 136 + ks * 32 + lq * 8];
      c[jt] = __builtin_amdgcn_mfma_f32_16x16x32_bf16(a[ks], b, c[jt], 0, 0, 0);
    }
  }
  __syncthreads();

  #pragma unroll
  for (int jt = 0; jt < 8; ++jt) {
    #pragma unroll
    for (int r = 0; r < 4; ++r) {
      hs[(wid * 16 + lq * 4 + r) * 132 + jt * 16 + lrow] = c[jt][r];
    }
  }
  __syncthreads();

  int q = t & 31, p = t >> 5;
  const float4 as4 = ((const float4*)att_src)[q];
  const float4 ad4 = ((const float4*)att_dst)[q];
  int head = q >> 2;
  #pragma unroll
  for (int rr = 0; rr < 8; ++rr) {
    int row = rr * 8 + p;
    int n = n0 + row;
    float4 v = *(const float4*)&hs[row * 132 + q * 4];
    float s = v.x * as4.x + v.y * as4.y + v.z * as4.z + v.w * as4.w;
    float d = v.x * ad4.x + v.y * ad4.y + v.z * ad4.z + v.w * ad4.w;
    s += __shfl_xor(s, 1); s += __shfl_xor(s, 2);
    d += __shfl_xor(d, 1); d += __shfl_xor(d, 2);
    if (n < nn) {
      uint2 pk;
      pk.x = (u32)f2bf(v.x) | ((u32)f2bf(v.y) << 16);
      pk.y = (u32)f2bf(v.z) | ((u32)f2bf(v.w) << 16);
      ((uint2*)(h + (size_t)n * 128))[q] = pk;
      if ((q & 3) == 0) { a_src[n * 8 + head] = s; a_dst[n * 8 + head] = d; }
    }
  }
}

// ---------- per-block LDS histogram of dst buckets ----------
__global__ __launch_bounds__(512) void ehist_kernel(
    const void* __restrict__ eidx, int E, int EP, int chunk,
    const int* __restrict__ flags, int* __restrict__ hist_g, int nbuk) {
  __shared__ int cnt[MAXBUK];
  int t = threadIdx.x, blk = blockIdx.x;
  if (t < MAXBUK) cnt[t] = 0;
  __syncthreads();
  int lo = blk * chunk, hi = min(lo + chunk, EP);
  int is64 = flags[0];
  for (int i = lo + t; i < hi; i += 512) {
    int d = (i < E) ? load_idx(eidx, E + i, is64) : (i - E);
    atomicAdd(&cnt[d >> 8], 1);
  }
  __syncthreads();
  if (t < nbuk) hist_g[t * NBLK + blk] = cnt[t];
}

// ---------- per-bucket scan of NBLK partial counts ----------
__global__ __launch_bounds__(256) void scan_blk(const int* __restrict__ in,
                                                int* __restrict__ out,
                                                int* __restrict__ bsums, int n) {
  int t = threadIdx.x;
  int i = blockIdx.x * 256 + t;
  int v = (i < n) ? in[i] : 0;
  int lane = t & 63, w = t >> 6;
  int s = v;
  #pragma unroll
  for (int off = 1; off < 64; off <<= 1) {
    int u = __shfl_up(s, off);
    if (lane >= off) s += u;
  }
  __shared__ int wsum[4];
  if (lane == 63) wsum[w] = s;
  __syncthreads();
  int add = 0;
  for (int k = 0; k < w; ++k) add += wsum[k];
  int incl = s + add;
  if (i < n) out[i] = incl - v;
  if (t == 255) bsums[blockIdx.x] = incl;
}

__global__ __launch_bounds__(1024) void scan_top(int* __restrict__ bsums, int nb) {
  int t = threadIdx.x;
  int v = (t < nb) ? bsums[t] : 0;
  int lane = t & 63, w = t >> 6;
  int s = v;
  #pragma unroll
  for (int off = 1; off < 64; off <<= 1) {
    int u = __shfl_up(s, off);
    if (lane >= off) s += u;
  }
  __shared__ int ws[16];
  if (lane == 63) ws[w] = s;
  __syncthreads();
  int add = 0;
  for (int k = 0; k < w; ++k) add += ws[k];
  if (t < nb) bsums[t] = s + add - v;
}

// ---------- scatter via LDS staging: dense per-run global writes ----------
__global__ __launch_bounds__(512) void escatter_kernel(
    const void* __restrict__ eidx, int E, int EP, int chunk,
    const int* __restrict__ flags, const int* __restrict__ hist_g,
    const int* __restrict__ pbase, const int* __restrict__ bsums,
    u32* __restrict__ pairs, int nbuk) {
  __shared__ int cnt[MAXBUK];
  __shared__ int lbase[MAXBUK];
  __shared__ int lcur[MAXBUK];
  __shared__ u32 buf[CHUNK_MAX];
  __shared__ int wsum[8];
  int t = threadIdx.x, blk = blockIdx.x;
  int v = 0;
  if (t < nbuk) { v = hist_g[t * NBLK + blk]; cnt[t] = v; }
  int lane = t & 63, w = t >> 6;
  int s = v;
  #pragma unroll
  for (int off = 1; off < 64; off <<= 1) {
    int u = __shfl_up(s, off);
    if (lane >= off) s += u;
  }
  if (lane == 63) wsum[w] = s;
  __syncthreads();
  int add = 0;
  for (int k = 0; k < w; ++k) add += wsum[k];
  if (t < nbuk) { lbase[t] = s + add - v; lcur[t] = s + add - v; }
  __syncthreads();
  int lo = blk * chunk, hi = min(lo + chunk, EP);
  int is64 = flags[0];
  for (int i = lo + t; i < hi; i += 512) {
    int sv, d;
    if (i < E) { sv = load_idx(eidx, i, is64); d = load_idx(eidx, E + i, is64); }
    else { sv = d = i - E; }
    int pos = atomicAdd(&lcur[d >> 8], 1);
    buf[pos] = ((u32)(d & 255) << 24) | (u32)sv;
  }
  __syncthreads();
  for (int b = w; b < nbuk; b += 8) {
    int n_b = cnt[b];
    int lb = lbase[b];
    int gb = pbase[b * NBLK + blk] + bsums[b];
    for (int k = lane; k < n_b; k += 64) {
      pairs[gb + k] = buf[lb + k];
    }
  }
}

// ---------- per-bucket local sort: LDS hist+scan, write offs/ends/ssrc ----------
__global__ __launch_bounds__(256) void bfinal_kernel(
    const u32* __restrict__ pairs, const int* __restrict__ pbase,
    const int* __restrict__ bsums,
    int* __restrict__ offs, int* __restrict__ ends, int* __restrict__ ssrc,
    int N, int EP, int nbuk) {
  int b = blockIdx.x, t = threadIdx.x;
  int nb0 = b << 8;
  __shared__ int cnt[256];
  __shared__ int cur[256];
  __shared__ int wsum[4];
  cnt[t] = 0;
  __syncthreads();
  int seg_start = pbase[b * NBLK] + bsums[b];
  int seg_end = (b + 1 < nbuk) ? (pbase[(b + 1) * NBLK] + bsums[b + 1]) : EP;
  for (int i = seg_start + t; i < seg_end; i += 256) {
    atomicAdd(&cnt[pairs[i] >> 24], 1);
  }
  __syncthreads();
  int v = cnt[t];
  int lane = t & 63, w = t >> 6;
  int s = v;
  #pragma unroll
  for (int off = 1; off < 64; off <<= 1) {
    int u = __shfl_up(s, off);
    if (lane >= off) s += u;
  }
  if (lane == 63) wsum[w] = s;
  __syncthreads();
  int add = 0;
  for (int k = 0; k < w; ++k) add += wsum[k];
  int excl = s + add - v;
  cur[t] = excl;
  int node = nb0 + t;
  if (node < N) { offs[node] = seg_start + excl; ends[node] = seg_start + excl + v; }
  __syncthreads();
  for (int i = seg_start + t; i < seg_end; i += 256) {
    u32 p = pairs[i];
    int pos = atomicAdd(&cur[p >> 24], 1);
    ssrc[seg_start + pos] = (int)(p & 0xFFFFFFu);
  }
}

// ---------- layer-1 aggregation + ELU + layer-2 projection ----------
// 16 lanes/node, 4 nodes/wave; clamped tail reads (hot-line re-read, ee=0 mask)
__global__ __launch_bounds__(256) void node1_kernel(
    const int* __restrict__ ssrc, const int* __restrict__ offs, const int* __restrict__ ends,
    const u16* __restrict__ h, const float* __restrict__ a_src, const float* __restrict__ a_dst,
    const float* __restrict__ b1, const float* __restrict__ W2,
    const float* __restrict__ att_s2, const float* __restrict__ att_d2,
    float4* __restrict__ rec, int nn) {
  int t = threadIdx.x;
  int wid = t >> 6, lane = t & 63;
  int grp = lane >> 4, lg = lane & 15;      // 4 node-groups of 16 lanes
  int n = blockIdx.x * 16 + wid * 4 + grp;
  bool nvalid = (n < nn);
  int nc = nvalid ? n : (nn - 1);
  int hh = lg >> 1;                          // head for this lane's 8 dims
  float adst = a_dst[nc * 8 + hh];
  int beg = offs[nc], end = ends[nc];
  int deg = nvalid ? (end - beg) : 0;
  int maxd = deg;
  maxd = max(maxd, __shfl_xor(maxd, 16));
  maxd = max(maxd, __shfl_xor(maxd, 32));    // wave-wide max degree
  float acc[8];
  #pragma unroll
  for (int k = 0; k < 8; ++k) acc[k] = 0.f;
  float dsum = 0.f;
  const u32* h32 = (const u32*)h;
  for (int it = 0; it < maxd; it += 4) {
    int s4[4]; float ea4[4]; uint4 v4[4];
    #pragma unroll
    for (int u = 0; u < 4; ++u) {
      int id = beg + it + u;
      s4[u] = ssrc[id < end ? id : end - 1];   // clamp to hot line
    }
    #pragma unroll
    for (int u = 0; u < 4; ++u) {
      v4[u]  = *(const uint4*)(h32 + s4[u] * 64 + lg * 4);
      ea4[u] = a_src[s4[u] * 8 + hh];
    }
    #pragma unroll
    for (int u = 0; u < 4; ++u) {
      float e = ea4[u] + adst;
      e = fmaxf(e, 0.2f * e);                 // leaky_relu
      float ee = (it + u < deg) ? __expf(e) : 0.f;
      dsum += ee;
      acc[0] = fmaf(ee, __uint_as_float(v4[u].x << 16),          acc[0]);
      acc[1] = fmaf(ee, __uint_as_float(v4[u].x & 0xFFFF0000u),  acc[1]);
      acc[2] = fmaf(ee, __uint_as_float(v4[u].y << 16),          acc[2]);
      acc[3] = fmaf(ee, __uint_as_float(v4[u].y & 0xFFFF0000u),  acc[3]);
      acc[4] = fmaf(ee, __uint_as_float(v4[u].z << 16),          acc[4]);
      acc[5] = fmaf(ee, __uint_as_float(v4[u].z & 0xFFFF0000u),  acc[5]);
      acc[6] = fmaf(ee, __uint_as_float(v4[u].w << 16),          acc[6]);
      acc[7] = fmaf(ee, __uint_as_float(v4[u].w & 0xFFFF0000u),  acc[7]);
    }
  }
  float inv = 1.f / dsum;                     // lane-local denominator
  float p0 = 0.f, p1 = 0.f;
  #pragma unroll
  for (int k = 0; k < 8; ++k) {
    int j = lg * 8 + k;
    float o = acc[k] * inv + b1[j];
    o = (o > 0.f) ? o : expm1f(o);            // ELU
    p0 = fmaf(o, W2[j * 2],     p0);
    p1 = fmaf(o, W2[j * 2 + 1], p1);
  }
  #pragma unroll
  for (int m = 1; m < 16; m <<= 1) { p0 += __shfl_xor(p0, m); p1 += __shfl_xor(p1, m); }
  if (nvalid && lg == 0) {
    rec[n] = make_float4(p0, p1,
                         p0 * att_s2[0] + p1 * att_s2[1],
                         p0 * att_d2[0] + p1 * att_d2[1]);
  }
}

// ---------- layer-2 aggregation + graph mean-pool (8-lane group per node) ----------
__global__ __launch_bounds__(256) void node2_kernel(
    const int* __restrict__ ssrc, const int* __restrict__ offs, const int* __restrict__ ends,
    const float4* __restrict__ rec, const float* __restrict__ b2,
    const void* __restrict__ batch, const int* __restrict__ flags,
    float* __restrict__ pool, int nn) {
  __shared__ float psum[128];
  __shared__ float pcnt[64];
  int t = threadIdx.x;
  if (t < 128) psum[t] = 0.f;
  if (t < 64) pcnt[t] = 0.f;
  __syncthreads();
  int grp = t >> 3, lane8 = t & 7;    // 32 groups of 8 lanes
  int b64 = flags[1];
  int n = blockIdx.x * 32 + grp;
  if (n < nn) {
    float adst = rec[n].w;
    int beg = offs[n], end = ends[n];
    float acc0 = 0.f, acc1 = 0.f, dsum = 0.f;
    for (int idx = beg + lane8; idx < end; idx += 8) {
      int s = ssrc[idx];
      float4 r = rec[s];                // one 16B gather: {p0,p1,as2,ad2}
      float e = r.z + adst;
      e = (e < 0.f) ? 0.2f * e : e;
      float ee = __expf(e);
      acc0 = fmaf(ee, r.x, acc0);
      acc1 = fmaf(ee, r.y, acc1);
      dsum += ee;
    }
    #pragma unroll
    for (int m = 1; m < 8; m <<= 1) {
      acc0 += __shfl_xor(acc0, m);
      acc1 += __shfl_xor(acc1, m);
      dsum += __shfl_xor(dsum, m);
    }
    if (lane8 == 0) {
      float o0 = acc0 / dsum + b2[0];
      float o1 = acc1 / dsum + b2[1];
      int g = load_idx(batch, n, b64);
      atomicAdd(&psum[g * 2], o0);
      atomicAdd(&psum[g * 2 + 1], o1);
      atomicAdd(&pcnt[g], 1.f);
    }
  }
  __syncthreads();
  if (t < 64 && pcnt[t] > 0.f) {
    atomicAdd(&pool[t * 2], psum[t * 2]);
    atomicAdd(&pool[t * 2 + 1], psum[t * 2 + 1]);
    atomicAdd(&pool[128 + t], pcnt[t]);
  }
}

// ---------- mean + log_softmax ----------
__global__ void finalize_kernel(const float* __restrict__ pool, float* __restrict__ out) {
  int g = threadIdx.x;
  if (g < 64) {
    float c = fmaxf(pool[128 + g], 1.f);
    float p0 = pool[g * 2] / c, p1 = pool[g * 2 + 1] / c;
    float m = fmaxf(p0, p1);
    float lse = m + logf(expf(p0 - m) + expf(p1 - m));
    out[g * 2] = p0 - lse;
    out[g * 2 + 1] = p1 - lse;
  }
}

extern "C" void kernel_launch(void* const* d_in, const int* in_sizes, int n_in,
                              void* d_out, int out_size, void* d_ws, size_t ws_size,
                              hipStream_t stream) {
  const float* x        = (const float*)d_in[0];
  const void* eidx      = d_in[1];
  const void* batch     = d_in[2];
  const float* W1       = (const float*)d_in[3];
  const float* att_src1 = (const float*)d_in[4];
  const float* att_dst1 = (const float*)d_in[5];
  const float* b1       = (const float*)d_in[6];
  const float* W2       = (const float*)d_in[7];
  const float* att_src2 = (const float*)d_in[8];
  const float* att_dst2 = (const float*)d_in[9];
  const float* b2       = (const float*)d_in[10];
  float* out = (float*)d_out;

  int N = in_sizes[0] / 128;
  int E = in_sizes[1] / 2;
  int EP = E + N;
  int NBUK = (N + 255) >> 8;         // <= MAXBUK for N <= 131072
  int NC = NBUK * NBLK;
  int chunk = (((EP + NBLK - 1) / NBLK) + 1) & ~1;   // <= CHUNK_MAX

  char* ws = (char*)d_ws;
  size_t o = 0;
  auto alloc = [&](size_t bytes) -> void* {
    void* p = ws + o;
    o += (bytes + 255) & ~(size_t)255;
    return p;
  };
  u16*   h      = (u16*)alloc((size_t)N * 128 * 2);    // 25.6 MB bf16
  u16*   Wtb    = (u16*)alloc(128 * 128 * 2);          // bf16 W1^T
  float* a_src1 = (float*)alloc((size_t)N * 8 * 4);
  float* a_dst1 = (float*)alloc((size_t)N * 8 * 4);
  int*   offs   = (int*)alloc((size_t)N * 4);
  int*   ends   = (int*)alloc((size_t)N * 4);
  int*   hist_g = (int*)alloc((size_t)NC * 4);         // 400 KB
  int*   pbase  = (int*)alloc((size_t)NC * 4);
  int*   bsums  = (int*)alloc((size_t)(NBUK + 1) * 4);
  u32*   pairs  = (u32*)alloc((size_t)EP * 4);         // 6.8 MB packed
  int*   ssrc   = (int*)alloc((size_t)EP * 4);
  float4* rec   = (float4*)alloc((size_t)N * 16);      // {p0,p1,as2,ad2}
  float* pool   = (float*)alloc(192 * 4);
  int*   flags  = (int*)alloc(2 * 4);

  prep_kernel<<<65, 256, 0, stream>>>(eidx, 2 * E, batch, N, W1, Wtb, pool, flags);
  gemm1_kernel<<<(N + 63) / 64, 256, 0, stream>>>(x, Wtb, att_src1, att_dst1,
                                                  h, a_src1, a_dst1, N);
  ehist_kernel<<<NBLK, 512, 0, stream>>>(eidx, E, EP, chunk, flags, hist_g, NBUK);
  scan_blk<<<NBUK, 256, 0, stream>>>(hist_g, pbase, bsums, NC);
  scan_top<<<1, 1024, 0, stream>>>(bsums, NBUK);
  escatter_kernel<<<NBLK, 512, 0, stream>>>(eidx, E, EP, chunk, flags, hist_g,
                                            pbase, bsums, pairs, NBUK);
  bfinal_kernel<<<NBUK, 256, 0, stream>>>(pairs, pbase, bsums, offs, ends, ssrc,
                                          N, EP, NBUK);
  node1_kernel<<<(N + 15) / 16, 256, 0, stream>>>(ssrc, offs, ends, h, a_src1, a_dst1,
                                                  b1, W2, att_src2, att_dst2,
                                                  rec, N);
  node2_kernel<<<(N + 31) / 32, 256, 0, stream>>>(ssrc, offs, ends, rec,
                                                  b2, batch, flags, pool, N);
  finalize_kernel<<<1, 64, 0, stream>>>(pool, out);
}